// Round 1
// baseline (385.143 us; speedup 1.0000x reference)
//
#include <hip/hip_runtime.h>
#include <hip/hip_bf16.h>

#define NROW 4096
#define D0   1024
#define DH1  512
#define DH2  256
#define DLAT 128
#define SLOPE 0.01f

typedef float f32x4 __attribute__((ext_vector_type(4)));
typedef __bf16 bf16x8 __attribute__((ext_vector_type(8)));
typedef short short8 __attribute__((ext_vector_type(8)));

// ---- async global->LDS 16B (wave-uniform base + lane*16 dest) ----
__device__ __forceinline__ void gload_lds16(const void* gp, void* lp) {
    __builtin_amdgcn_global_load_lds(
        (const __attribute__((address_space(1))) void*)(unsigned long long)gp,
        (__attribute__((address_space(3))) void*)(unsigned int)(unsigned long long)lp,
        16, 0, 0);
}

// Stage a 128x32 bf16 tile (rows row0..row0+127, cols k0..k0+31 of a [rows][ldK]
// row-major matrix) into LDS laid out [128][32] shorts, with k-slot swizzle:
// stored slot t holds data slot s = t ^ ((row>>1)&3). LDS dest stays linear
// (lane*16) as global_load_lds requires; the swizzle is applied to the SOURCE.
__device__ __forceinline__ void stage_tile(const __hip_bfloat16* __restrict__ src,
                                           int row0, int ldK, int k0,
                                           short* lds, int wave, int lane) {
#pragma unroll
    for (int i = 0; i < 2; ++i) {
        int lr = wave * 32 + i * 16 + (lane >> 2);   // tile row 0..127
        int t  = lane & 3;                            // stored slot
        int s  = t ^ ((lr >> 1) & 3);                 // source k-slot
        const __hip_bfloat16* gp = src + (size_t)(row0 + lr) * ldK + k0 + s * 8;
        short* lp = lds + lr * 32 + t * 8;            // == wave base + lane*16B
        gload_lds16((const void*)gp, (void*)lp);
    }
}

// Read one 16x32 MFMA operand fragment: lane l -> row (l&15)+... , k-slot l>>4.
__device__ __forceinline__ bf16x8 read_frag(const short* lds, int row, int kslot) {
    int pos = kslot ^ ((row >> 1) & 3);
    short8 v = *reinterpret_cast<const short8*>(lds + row * 32 + pos * 8);
    union { short8 s; bf16x8 b; } u; u.s = v; return u.b;
}

// ---- split-precision GEMM: C = lrelu(A @ W^T + b) ----
// A: [M][K] as hi/lo bf16, W: [N][K] as hi/lo bf16 (nn.Linear layout).
// 3-MFMA split: ah*bh + ah*bl + al*bh  (residual ~2^-18 relative).
__global__ __launch_bounds__(256) void gemm_lrelu(
    const __hip_bfloat16* __restrict__ Ah, const __hip_bfloat16* __restrict__ Al,
    const __hip_bfloat16* __restrict__ Wh, const __hip_bfloat16* __restrict__ Wl,
    const float* __restrict__ bias,
    float* __restrict__ Cf, __hip_bfloat16* __restrict__ Ch, __hip_bfloat16* __restrict__ Cl,
    int N, int K)
{
    __shared__ short sAh[128 * 32];
    __shared__ short sAl[128 * 32];
    __shared__ short sBh[128 * 32];
    __shared__ short sBl[128 * 32];
    const int tid = threadIdx.x, lane = tid & 63, wave = tid >> 6;
    const int wm = wave >> 1, wn = wave & 1;
    const int bm = blockIdx.x, bn = blockIdx.y;

    f32x4 acc[4][4] = {};
    const int nk = K >> 5;
    for (int ks = 0; ks < nk; ++ks) {
        __syncthreads();   // protect LDS from prior-iter readers
        stage_tile(Ah, bm * 128, K, ks * 32, sAh, wave, lane);
        stage_tile(Al, bm * 128, K, ks * 32, sAl, wave, lane);
        stage_tile(Wh, bn * 128, K, ks * 32, sBh, wave, lane);
        stage_tile(Wl, bn * 128, K, ks * 32, sBl, wave, lane);
        __syncthreads();   // drains vmcnt -> tiles resident
        bf16x8 ah[4], al[4], bh[4], bl[4];
#pragma unroll
        for (int m = 0; m < 4; ++m) {
            int r = wm * 64 + m * 16 + (lane & 15);
            ah[m] = read_frag(sAh, r, lane >> 4);
            al[m] = read_frag(sAl, r, lane >> 4);
        }
#pragma unroll
        for (int n = 0; n < 4; ++n) {
            int r = wn * 64 + n * 16 + (lane & 15);
            bh[n] = read_frag(sBh, r, lane >> 4);
            bl[n] = read_frag(sBl, r, lane >> 4);
        }
#pragma unroll
        for (int m = 0; m < 4; ++m)
#pragma unroll
            for (int n = 0; n < 4; ++n) {
                acc[m][n] = __builtin_amdgcn_mfma_f32_16x16x32_bf16(ah[m], bh[n], acc[m][n], 0, 0, 0);
                acc[m][n] = __builtin_amdgcn_mfma_f32_16x16x32_bf16(ah[m], bl[n], acc[m][n], 0, 0, 0);
                acc[m][n] = __builtin_amdgcn_mfma_f32_16x16x32_bf16(al[m], bh[n], acc[m][n], 0, 0, 0);
            }
    }

    float bcol[4];
#pragma unroll
    for (int n = 0; n < 4; ++n) bcol[n] = bias[bn * 128 + wn * 64 + n * 16 + (lane & 15)];

#pragma unroll
    for (int m = 0; m < 4; ++m)
#pragma unroll
        for (int n = 0; n < 4; ++n)
#pragma unroll
            for (int j = 0; j < 4; ++j) {
                int grow = bm * 128 + wm * 64 + m * 16 + (lane >> 4) * 4 + j;
                int gcol = bn * 128 + wn * 64 + n * 16 + (lane & 15);
                float v = acc[m][n][j] + bcol[n];
                v = v >= 0.f ? v : SLOPE * v;
                size_t idx = (size_t)grow * N + gcol;
                if (Cf) Cf[idx] = v;
                if (Ch) {
                    __hip_bfloat16 h = __float2bfloat16(v);
                    Ch[idx] = h;
                    Cl[idx] = __float2bfloat16(v - __bfloat162float(h));
                }
            }
}

// ---- fused pairwise-distance statistics ----
// For upper-triangular 128x128 blocks of the 4096x4096 pair grid:
// G1 = x x^T (K=1024), G2 = latent latent^T (K=128), distances in-register,
// accumulate S1,S2,S11,S22,S12 (weight 2 off-diag blocks) into fp64 atomics.
__global__ __launch_bounds__(256) void pairwise_corr(
    const __hip_bfloat16* __restrict__ Xh, const __hip_bfloat16* __restrict__ Lh,
    const float* __restrict__ r1, const float* __restrict__ r2,
    double* __restrict__ stats)
{
    const int bm = blockIdx.x, bn = blockIdx.y;
    if (bm > bn) return;   // symmetry: upper triangle only
    __shared__ short sA[128 * 32];
    __shared__ short sB[128 * 32];
    const int tid = threadIdx.x, lane = tid & 63, wave = tid >> 6;
    const int wm = wave >> 1, wn = wave & 1;

    f32x4 acc[4][4] = {};
#pragma unroll 1
    for (int ks = 0; ks < 32; ++ks) {
        __syncthreads();
        stage_tile(Xh, bm * 128, D0, ks * 32, sA, wave, lane);
        stage_tile(Xh, bn * 128, D0, ks * 32, sB, wave, lane);
        __syncthreads();
        bf16x8 a[4], b[4];
#pragma unroll
        for (int m = 0; m < 4; ++m) a[m] = read_frag(sA, wm * 64 + m * 16 + (lane & 15), lane >> 4);
#pragma unroll
        for (int n = 0; n < 4; ++n) b[n] = read_frag(sB, wn * 64 + n * 16 + (lane & 15), lane >> 4);
#pragma unroll
        for (int m = 0; m < 4; ++m)
#pragma unroll
            for (int n = 0; n < 4; ++n)
                acc[m][n] = __builtin_amdgcn_mfma_f32_16x16x32_bf16(a[m], b[n], acc[m][n], 0, 0, 0);
    }
    // Gram -> distance, in place (diag forced to exact 0, matching reference)
#pragma unroll
    for (int m = 0; m < 4; ++m)
#pragma unroll
        for (int n = 0; n < 4; ++n)
#pragma unroll
            for (int j = 0; j < 4; ++j) {
                int gi = bm * 128 + wm * 64 + m * 16 + (lane >> 4) * 4 + j;
                int gj = bn * 128 + wn * 64 + n * 16 + (lane & 15);
                float sq = r1[gi] + r1[gj] - 2.0f * acc[m][n][j];
                acc[m][n][j] = (gi == gj || sq <= 0.f) ? 0.f : sqrtf(sq);
            }

    f32x4 acc2[4][4] = {};
#pragma unroll 1
    for (int ks = 0; ks < 4; ++ks) {
        __syncthreads();
        stage_tile(Lh, bm * 128, DLAT, ks * 32, sA, wave, lane);
        stage_tile(Lh, bn * 128, DLAT, ks * 32, sB, wave, lane);
        __syncthreads();
        bf16x8 a[4], b[4];
#pragma unroll
        for (int m = 0; m < 4; ++m) a[m] = read_frag(sA, wm * 64 + m * 16 + (lane & 15), lane >> 4);
#pragma unroll
        for (int n = 0; n < 4; ++n) b[n] = read_frag(sB, wn * 64 + n * 16 + (lane & 15), lane >> 4);
#pragma unroll
        for (int m = 0; m < 4; ++m)
#pragma unroll
            for (int n = 0; n < 4; ++n)
                acc2[m][n] = __builtin_amdgcn_mfma_f32_16x16x32_bf16(a[m], b[n], acc2[m][n], 0, 0, 0);
    }

    float s1 = 0.f, s2 = 0.f, s11 = 0.f, s22 = 0.f, s12 = 0.f;
#pragma unroll
    for (int m = 0; m < 4; ++m)
#pragma unroll
        for (int n = 0; n < 4; ++n)
#pragma unroll
            for (int j = 0; j < 4; ++j) {
                int gi = bm * 128 + wm * 64 + m * 16 + (lane >> 4) * 4 + j;
                int gj = bn * 128 + wn * 64 + n * 16 + (lane & 15);
                float d1v = acc[m][n][j];
                float sq2 = r2[gi] + r2[gj] - 2.0f * acc2[m][n][j];
                float d2v = (gi == gj || sq2 <= 0.f) ? 0.f : sqrtf(sq2);
                s1 += d1v; s2 += d2v;
                s11 += d1v * d1v; s22 += d2v * d2v; s12 += d1v * d2v;
            }

    float vals[5] = { s1, s2, s11, s22, s12 };
#pragma unroll
    for (int q = 0; q < 5; ++q)
        for (int off = 32; off; off >>= 1) vals[q] += __shfl_down(vals[q], off);

    __syncthreads();                 // done reading sA/sB; reuse as reduce buffer
    float* red = (float*)sA;
    if (lane == 0) {
#pragma unroll
        for (int q = 0; q < 5; ++q) red[wave * 5 + q] = vals[q];
    }
    __syncthreads();
    if (tid == 0) {
        double w = (bm == bn) ? 1.0 : 2.0;
#pragma unroll
        for (int q = 0; q < 5; ++q) {
            double t = (double)red[q] + (double)red[5 + q] + (double)red[10 + q] + (double)red[15 + q];
            atomicAdd(&stats[q], w * t);
        }
    }
}

// ---- helpers ----
__global__ void split_f32(const float* __restrict__ in, __hip_bfloat16* __restrict__ hi,
                          __hip_bfloat16* __restrict__ lo, int n) {
    int i = (blockIdx.x * blockDim.x + threadIdx.x) * 4;
    if (i >= n) return;
    float4 f = *(const float4*)(in + i);
    float fv[4] = { f.x, f.y, f.z, f.w };
#pragma unroll
    for (int j = 0; j < 4; ++j) {
        __hip_bfloat16 h = __float2bfloat16(fv[j]);
        hi[i + j] = h;
        lo[i + j] = __float2bfloat16(fv[j] - __bfloat162float(h));
    }
}

__global__ void row_sumsq(const float* __restrict__ X, float* __restrict__ r, int K) {
    int lane = threadIdx.x & 63;
    int row = blockIdx.x * (blockDim.x >> 6) + (threadIdx.x >> 6);
    const float* p = X + (size_t)row * K;
    float s = 0.f;
    for (int k = lane; k < K; k += 64) { float v = p[k]; s += v * v; }
    for (int off = 32; off; off >>= 1) s += __shfl_down(s, off);
    if (lane == 0) r[row] = s;
}

__global__ void init_stats(double* stats) {
    if (threadIdx.x < 5) stats[threadIdx.x] = 0.0;
}

__global__ void finalize_corr(const double* __restrict__ stats, float* __restrict__ corr_out) {
    double n = (double)NROW * (double)NROW;
    double s1 = stats[0], s2 = stats[1], s11 = stats[2], s22 = stats[3], s12 = stats[4];
    double m1 = s1 / n, m2 = s2 / n;
    double cov = s12 / n - m1 * m2;                  // biased (mean)
    double v1 = (s11 - n * m1 * m1) / (n - 1.0);     // unbiased (ddof=1)
    double v2 = (s22 - n * m2 * m2) / (n - 1.0);
    corr_out[0] = (float)(cov / sqrt(v1 * v2));
}

extern "C" void kernel_launch(void* const* d_in, const int* in_sizes, int n_in,
                              void* d_out, int out_size, void* d_ws, size_t ws_size,
                              hipStream_t stream) {
    const float* x   = (const float*)d_in[0];
    const float* We1 = (const float*)d_in[1];  const float* be1 = (const float*)d_in[2];
    const float* We2 = (const float*)d_in[3];  const float* be2 = (const float*)d_in[4];
    const float* We3 = (const float*)d_in[5];  const float* be3 = (const float*)d_in[6];
    const float* Wd1 = (const float*)d_in[7];  const float* bd1 = (const float*)d_in[8];
    const float* Wd2 = (const float*)d_in[9];  const float* bd2 = (const float*)d_in[10];
    const float* Wd3 = (const float*)d_in[11]; const float* bd3 = (const float*)d_in[12];
    float* out = (float*)d_out;

    char* ws = (char*)d_ws;
    size_t off = 0;
    auto alloc = [&](size_t bytes) -> char* {
        char* p = ws + off; off += (bytes + 255) & ~(size_t)255; return p;
    };
    typedef __hip_bfloat16 bf;
    bf* xh  = (bf*)alloc((size_t)NROW * D0 * 2);   bf* xl  = (bf*)alloc((size_t)NROW * D0 * 2);
    bf* w1h = (bf*)alloc((size_t)DH1 * D0 * 2);    bf* w1l = (bf*)alloc((size_t)DH1 * D0 * 2);
    bf* w2h = (bf*)alloc((size_t)DH2 * DH1 * 2);   bf* w2l = (bf*)alloc((size_t)DH2 * DH1 * 2);
    bf* w3h = (bf*)alloc((size_t)DLAT * DH2 * 2);  bf* w3l = (bf*)alloc((size_t)DLAT * DH2 * 2);
    bf* w4h = (bf*)alloc((size_t)DH2 * DLAT * 2);  bf* w4l = (bf*)alloc((size_t)DH2 * DLAT * 2);
    bf* w5h = (bf*)alloc((size_t)DH1 * DH2 * 2);   bf* w5l = (bf*)alloc((size_t)DH1 * DH2 * 2);
    bf* w6h = (bf*)alloc((size_t)D0 * DH1 * 2);    bf* w6l = (bf*)alloc((size_t)D0 * DH1 * 2);
    bf* h1h = (bf*)alloc((size_t)NROW * DH1 * 2);  bf* h1l = (bf*)alloc((size_t)NROW * DH1 * 2);
    bf* h2h = (bf*)alloc((size_t)NROW * DH2 * 2);  bf* h2l = (bf*)alloc((size_t)NROW * DH2 * 2);
    bf* lth = (bf*)alloc((size_t)NROW * DLAT * 2); bf* ltl = (bf*)alloc((size_t)NROW * DLAT * 2);
    float* ltf = (float*)alloc((size_t)NROW * DLAT * 4);
    bf* d4h = (bf*)alloc((size_t)NROW * DH2 * 2);  bf* d4l = (bf*)alloc((size_t)NROW * DH2 * 2);
    bf* d5h = (bf*)alloc((size_t)NROW * DH1 * 2);  bf* d5l = (bf*)alloc((size_t)NROW * DH1 * 2);
    float* r1v = (float*)alloc((size_t)NROW * 4);
    float* r2v = (float*)alloc((size_t)NROW * 4);
    double* stats = (double*)alloc(5 * 8);

    auto splitN = [&](const float* src, bf* hi, bf* lo, int n) {
        split_f32<<<(n / 4 + 255) / 256, 256, 0, stream>>>(src, hi, lo, n);
    };
    splitN(x,   xh,  xl,  NROW * D0);
    splitN(We1, w1h, w1l, DH1 * D0);
    splitN(We2, w2h, w2l, DH2 * DH1);
    splitN(We3, w3h, w3l, DLAT * DH2);
    splitN(Wd1, w4h, w4l, DH2 * DLAT);
    splitN(Wd2, w5h, w5l, DH1 * DH2);
    splitN(Wd3, w6h, w6l, D0 * DH1);

    row_sumsq<<<NROW / 4, 256, 0, stream>>>(x, r1v, D0);
    init_stats<<<1, 64, 0, stream>>>(stats);

    // encoder
    gemm_lrelu<<<dim3(NROW / 128, DH1 / 128), 256, 0, stream>>>(
        xh, xl, w1h, w1l, be1, nullptr, h1h, h1l, DH1, D0);
    gemm_lrelu<<<dim3(NROW / 128, DH2 / 128), 256, 0, stream>>>(
        h1h, h1l, w2h, w2l, be2, nullptr, h2h, h2l, DH2, DH1);
    gemm_lrelu<<<dim3(NROW / 128, DLAT / 128), 256, 0, stream>>>(
        h2h, h2l, w3h, w3l, be3, ltf, lth, ltl, DLAT, DH2);
    row_sumsq<<<NROW / 4, 256, 0, stream>>>(ltf, r2v, DLAT);
    // decoder
    gemm_lrelu<<<dim3(NROW / 128, DH2 / 128), 256, 0, stream>>>(
        lth, ltl, w4h, w4l, bd1, nullptr, d4h, d4l, DH2, DLAT);
    gemm_lrelu<<<dim3(NROW / 128, DH1 / 128), 256, 0, stream>>>(
        d4h, d4l, w5h, w5l, bd2, nullptr, d5h, d5l, DH1, DH2);
    gemm_lrelu<<<dim3(NROW / 128, D0 / 128), 256, 0, stream>>>(
        d5h, d5l, w6h, w6l, bd3, out, nullptr, nullptr, D0, DH1);

    // fused pairwise-distance correlation statistics
    pairwise_corr<<<dim3(32, 32), 256, 0, stream>>>(xh, lth, r1v, r2v, stats);
    finalize_corr<<<1, 1, 0, stream>>>(stats, out + (size_t)NROW * D0);
}

// Round 2
// 335.182 us; speedup vs baseline: 1.1491x; 1.1491x over previous
//
#include <hip/hip_runtime.h>
#include <hip/hip_bf16.h>

#define NROW 4096
#define D0   1024
#define DH1  512
#define DH2  256
#define DLAT 128
#define SLOPE 0.01f

typedef float f32x4 __attribute__((ext_vector_type(4)));
typedef __bf16 bf16x8 __attribute__((ext_vector_type(8)));
typedef short short8 __attribute__((ext_vector_type(8)));

// ---- async global->LDS 16B (wave-uniform base + lane*16 dest) ----
__device__ __forceinline__ void gload_lds16(const void* gp, void* lp) {
    __builtin_amdgcn_global_load_lds(
        (const __attribute__((address_space(1))) void*)(unsigned long long)gp,
        (__attribute__((address_space(3))) void*)(unsigned int)(unsigned long long)lp,
        16, 0, 0);
}

// Stage a 128x32 bf16 tile into LDS [128][32] shorts with k-slot swizzle:
// stored slot t holds source slot s = t ^ ((row>>1)&3). LDS dest stays linear
// (lane*16B) as global_load_lds requires; swizzle applied to the SOURCE addr.
__device__ __forceinline__ void stage_tile(const __hip_bfloat16* __restrict__ src,
                                           int row0, int ldK, int k0,
                                           short* lds, int wave, int lane) {
#pragma unroll
    for (int i = 0; i < 2; ++i) {
        int lr = wave * 32 + i * 16 + (lane >> 2);   // tile row 0..127
        int t  = lane & 3;                            // stored slot
        int s  = t ^ ((lr >> 1) & 3);                 // source k-slot
        const __hip_bfloat16* gp = src + (size_t)(row0 + lr) * ldK + k0 + s * 8;
        short* lp = lds + lr * 32 + t * 8;            // wave base + lane*16B
        gload_lds16((const void*)gp, (void*)lp);
    }
}

// Read one 16x32 MFMA operand fragment (undo swizzle on the read side).
__device__ __forceinline__ bf16x8 read_frag(const short* lds, int row, int kslot) {
    int pos = kslot ^ ((row >> 1) & 3);
    short8 v = *reinterpret_cast<const short8*>(lds + row * 32 + pos * 8);
    union { short8 s; bf16x8 b; } u; u.s = v; return u.b;
}

// ---- split-precision GEMM: C = lrelu(A @ W^T + b), 2-phase pipelined ----
// 3-MFMA split: ah*bh + ah*bl + al*bh (residual ~2^-18 relative).
__global__ __launch_bounds__(256) void gemm_lrelu(
    const __hip_bfloat16* __restrict__ Ah, const __hip_bfloat16* __restrict__ Al,
    const __hip_bfloat16* __restrict__ Wh, const __hip_bfloat16* __restrict__ Wl,
    const float* __restrict__ bias,
    float* __restrict__ Cf, __hip_bfloat16* __restrict__ Ch, __hip_bfloat16* __restrict__ Cl,
    int N, int K)
{
    __shared__ short sAh[2][128 * 32];
    __shared__ short sAl[2][128 * 32];
    __shared__ short sBh[2][128 * 32];
    __shared__ short sBl[2][128 * 32];
    const int tid = threadIdx.x, lane = tid & 63, wave = tid >> 6;
    const int wm = wave >> 1, wn = wave & 1;
    const int bm = blockIdx.x, bn = blockIdx.y;
    const int nk = K >> 5;

    f32x4 acc[4][4] = {};

    auto stage_all = [&](int buf, int ks) {
        stage_tile(Ah, bm * 128, K, ks * 32, sAh[buf], wave, lane);
        stage_tile(Al, bm * 128, K, ks * 32, sAl[buf], wave, lane);
        stage_tile(Wh, bn * 128, K, ks * 32, sBh[buf], wave, lane);
        stage_tile(Wl, bn * 128, K, ks * 32, sBl[buf], wave, lane);
    };

    stage_all(0, 0);
    __syncthreads();                     // tile 0 resident
    int cur = 0;
#pragma unroll 1
    for (int ks = 0; ks < nk; ++ks) {
        if (ks + 1 < nk) stage_all(cur ^ 1, ks + 1);   // issue next-tile loads
        bf16x8 ah[4], al[4], bh[4], bl[4];
#pragma unroll
        for (int m = 0; m < 4; ++m) {
            int r = wm * 64 + m * 16 + (lane & 15);
            ah[m] = read_frag(sAh[cur], r, lane >> 4);
            al[m] = read_frag(sAl[cur], r, lane >> 4);
        }
#pragma unroll
        for (int n = 0; n < 4; ++n) {
            int r = wn * 64 + n * 16 + (lane & 15);
            bh[n] = read_frag(sBh[cur], r, lane >> 4);
            bl[n] = read_frag(sBl[cur], r, lane >> 4);
        }
#pragma unroll
        for (int m = 0; m < 4; ++m)
#pragma unroll
            for (int n = 0; n < 4; ++n) {
                acc[m][n] = __builtin_amdgcn_mfma_f32_16x16x32_bf16(ah[m], bh[n], acc[m][n], 0, 0, 0);
                acc[m][n] = __builtin_amdgcn_mfma_f32_16x16x32_bf16(ah[m], bl[n], acc[m][n], 0, 0, 0);
                acc[m][n] = __builtin_amdgcn_mfma_f32_16x16x32_bf16(al[m], bh[n], acc[m][n], 0, 0, 0);
            }
        __syncthreads();   // drains vmcnt(0): next tile resident; LDS safe to reuse
        cur ^= 1;
    }

    float bcol[4];
#pragma unroll
    for (int n = 0; n < 4; ++n) bcol[n] = bias[bn * 128 + wn * 64 + n * 16 + (lane & 15)];

#pragma unroll
    for (int m = 0; m < 4; ++m)
#pragma unroll
        for (int n = 0; n < 4; ++n)
#pragma unroll
            for (int j = 0; j < 4; ++j) {
                int grow = bm * 128 + wm * 64 + m * 16 + (lane >> 4) * 4 + j;
                int gcol = bn * 128 + wn * 64 + n * 16 + (lane & 15);
                float v = acc[m][n][j] + bcol[n];
                v = v >= 0.f ? v : SLOPE * v;
                size_t idx = (size_t)grow * N + gcol;
                if (Cf) Cf[idx] = v;
                if (Ch) {
                    __hip_bfloat16 h = __float2bfloat16(v);
                    Ch[idx] = h;
                    Cl[idx] = __float2bfloat16(v - __bfloat162float(h));
                }
            }
}

// ---- fused pairwise-distance statistics, 2-phase pipelined ----
// Triangle-only launch (528 blocks). Merged 36-step loop: steps 0..31 build
// G1 = x x^T (K=1024), steps 32..35 build G2 = latent latent^T (K=128).
// Distances in-register; S1,S2,S11,S22,S12 -> fp64 atomics (weight 2 off-diag).
__global__ __launch_bounds__(256) void pairwise_corr(
    const __hip_bfloat16* __restrict__ Xh, const __hip_bfloat16* __restrict__ Lh,
    const float* __restrict__ r1, const float* __restrict__ r2,
    double* __restrict__ stats)
{
    int rem = blockIdx.x, bm = 0;
    while (rem >= 32 - bm) { rem -= 32 - bm; ++bm; }
    const int bn = bm + rem;                       // bm <= bn

    __shared__ short sA[2][128 * 32];
    __shared__ short sB[2][128 * 32];
    const int tid = threadIdx.x, lane = tid & 63, wave = tid >> 6;
    const int wm = wave >> 1, wn = wave & 1;

    f32x4 acc[4][4] = {};
    f32x4 acc2[4][4] = {};

    auto stage_step = [&](int buf, int t) {
        if (t < 32) {
            stage_tile(Xh, bm * 128, D0, t * 32, sA[buf], wave, lane);
            stage_tile(Xh, bn * 128, D0, t * 32, sB[buf], wave, lane);
        } else {
            int k0 = (t - 32) * 32;
            stage_tile(Lh, bm * 128, DLAT, k0, sA[buf], wave, lane);
            stage_tile(Lh, bn * 128, DLAT, k0, sB[buf], wave, lane);
        }
    };

    stage_step(0, 0);
    __syncthreads();
    int cur = 0;
#pragma unroll 1
    for (int t = 0; t < 36; ++t) {
        if (t + 1 < 36) stage_step(cur ^ 1, t + 1);
        bf16x8 a[4], b[4];
#pragma unroll
        for (int m = 0; m < 4; ++m) a[m] = read_frag(sA[cur], wm * 64 + m * 16 + (lane & 15), lane >> 4);
#pragma unroll
        for (int n = 0; n < 4; ++n) b[n] = read_frag(sB[cur], wn * 64 + n * 16 + (lane & 15), lane >> 4);
        if (t < 32) {
#pragma unroll
            for (int m = 0; m < 4; ++m)
#pragma unroll
                for (int n = 0; n < 4; ++n)
                    acc[m][n] = __builtin_amdgcn_mfma_f32_16x16x32_bf16(a[m], b[n], acc[m][n], 0, 0, 0);
        } else {
#pragma unroll
            for (int m = 0; m < 4; ++m)
#pragma unroll
                for (int n = 0; n < 4; ++n)
                    acc2[m][n] = __builtin_amdgcn_mfma_f32_16x16x32_bf16(a[m], b[n], acc2[m][n], 0, 0, 0);
        }
        __syncthreads();
        cur ^= 1;
    }

    float s1 = 0.f, s2 = 0.f, s11 = 0.f, s22 = 0.f, s12 = 0.f;
#pragma unroll
    for (int m = 0; m < 4; ++m)
#pragma unroll
        for (int n = 0; n < 4; ++n)
#pragma unroll
            for (int j = 0; j < 4; ++j) {
                int gi = bm * 128 + wm * 64 + m * 16 + (lane >> 4) * 4 + j;
                int gj = bn * 128 + wn * 64 + n * 16 + (lane & 15);
                float sq1 = r1[gi] + r1[gj] - 2.0f * acc[m][n][j];
                float d1v = (gi == gj || sq1 <= 0.f) ? 0.f : sqrtf(sq1);
                float sq2 = r2[gi] + r2[gj] - 2.0f * acc2[m][n][j];
                float d2v = (gi == gj || sq2 <= 0.f) ? 0.f : sqrtf(sq2);
                s1 += d1v; s2 += d2v;
                s11 += d1v * d1v; s22 += d2v * d2v; s12 += d1v * d2v;
            }

    float vals[5] = { s1, s2, s11, s22, s12 };
#pragma unroll
    for (int q = 0; q < 5; ++q)
        for (int off = 32; off; off >>= 1) vals[q] += __shfl_down(vals[q], off);

    __syncthreads();                 // done with LDS; reuse as reduce buffer
    float* red = (float*)sA;
    if (lane == 0) {
#pragma unroll
        for (int q = 0; q < 5; ++q) red[wave * 5 + q] = vals[q];
    }
    __syncthreads();
    if (tid == 0) {
        double w = (bm == bn) ? 1.0 : 2.0;
#pragma unroll
        for (int q = 0; q < 5; ++q) {
            double tt = (double)red[q] + (double)red[5 + q] + (double)red[10 + q] + (double)red[15 + q];
            atomicAdd(&stats[q], w * tt);
        }
    }
}

// ---- fused hi/lo split for x + all 6 weights (one launch) ----
struct SplitSeg { const float* src; __hip_bfloat16* hi; __hip_bfloat16* lo; };
struct SplitArgs { SplitSeg s[7]; unsigned cum4[8]; };  // boundaries in float4 units

__global__ void split_many(SplitArgs A, int total4) {
    int v = blockIdx.x * blockDim.x + threadIdx.x;
    if (v >= total4) return;
    int si = 0;
#pragma unroll
    for (int i = 1; i < 7; ++i) si = (v >= (int)A.cum4[i]) ? i : si;
    int local = v - (int)A.cum4[si];
    const float* src = A.s[si].src;
    __hip_bfloat16* hi = A.s[si].hi;
    __hip_bfloat16* lo = A.s[si].lo;
    float4 f = *(const float4*)(src + (size_t)local * 4);
    float fv[4] = { f.x, f.y, f.z, f.w };
#pragma unroll
    for (int j = 0; j < 4; ++j) {
        __hip_bfloat16 h = __float2bfloat16(fv[j]);
        hi[local * 4 + j] = h;
        lo[local * 4 + j] = __float2bfloat16(fv[j] - __bfloat162float(h));
    }
}

__global__ void row_sumsq(const float* __restrict__ X, float* __restrict__ r, int K) {
    int lane = threadIdx.x & 63;
    int row = blockIdx.x * (blockDim.x >> 6) + (threadIdx.x >> 6);
    const float* p = X + (size_t)row * K;
    float s = 0.f;
    for (int k = lane; k < K; k += 64) { float v = p[k]; s += v * v; }
    for (int off = 32; off; off >>= 1) s += __shfl_down(s, off);
    if (lane == 0) r[row] = s;
}

__global__ void init_stats(double* stats) {
    if (threadIdx.x < 5) stats[threadIdx.x] = 0.0;
}

__global__ void finalize_corr(const double* __restrict__ stats, float* __restrict__ corr_out) {
    double n = (double)NROW * (double)NROW;
    double s1 = stats[0], s2 = stats[1], s11 = stats[2], s22 = stats[3], s12 = stats[4];
    double m1 = s1 / n, m2 = s2 / n;
    double cov = s12 / n - m1 * m2;                  // biased (mean)
    double v1 = (s11 - n * m1 * m1) / (n - 1.0);     // unbiased (ddof=1)
    double v2 = (s22 - n * m2 * m2) / (n - 1.0);
    corr_out[0] = (float)(cov / sqrt(v1 * v2));
}

extern "C" void kernel_launch(void* const* d_in, const int* in_sizes, int n_in,
                              void* d_out, int out_size, void* d_ws, size_t ws_size,
                              hipStream_t stream) {
    const float* x   = (const float*)d_in[0];
    const float* We1 = (const float*)d_in[1];  const float* be1 = (const float*)d_in[2];
    const float* We2 = (const float*)d_in[3];  const float* be2 = (const float*)d_in[4];
    const float* We3 = (const float*)d_in[5];  const float* be3 = (const float*)d_in[6];
    const float* Wd1 = (const float*)d_in[7];  const float* bd1 = (const float*)d_in[8];
    const float* Wd2 = (const float*)d_in[9];  const float* bd2 = (const float*)d_in[10];
    const float* Wd3 = (const float*)d_in[11]; const float* bd3 = (const float*)d_in[12];
    float* out = (float*)d_out;

    char* ws = (char*)d_ws;
    size_t off = 0;
    auto alloc = [&](size_t bytes) -> char* {
        char* p = ws + off; off += (bytes + 255) & ~(size_t)255; return p;
    };
    typedef __hip_bfloat16 bf;
    bf* xh  = (bf*)alloc((size_t)NROW * D0 * 2);   bf* xl  = (bf*)alloc((size_t)NROW * D0 * 2);
    bf* w1h = (bf*)alloc((size_t)DH1 * D0 * 2);    bf* w1l = (bf*)alloc((size_t)DH1 * D0 * 2);
    bf* w2h = (bf*)alloc((size_t)DH2 * DH1 * 2);   bf* w2l = (bf*)alloc((size_t)DH2 * DH1 * 2);
    bf* w3h = (bf*)alloc((size_t)DLAT * DH2 * 2);  bf* w3l = (bf*)alloc((size_t)DLAT * DH2 * 2);
    bf* w4h = (bf*)alloc((size_t)DH2 * DLAT * 2);  bf* w4l = (bf*)alloc((size_t)DH2 * DLAT * 2);
    bf* w5h = (bf*)alloc((size_t)DH1 * DH2 * 2);   bf* w5l = (bf*)alloc((size_t)DH1 * DH2 * 2);
    bf* w6h = (bf*)alloc((size_t)D0 * DH1 * 2);    bf* w6l = (bf*)alloc((size_t)D0 * DH1 * 2);
    bf* h1h = (bf*)alloc((size_t)NROW * DH1 * 2);  bf* h1l = (bf*)alloc((size_t)NROW * DH1 * 2);
    bf* h2h = (bf*)alloc((size_t)NROW * DH2 * 2);  bf* h2l = (bf*)alloc((size_t)NROW * DH2 * 2);
    bf* lth = (bf*)alloc((size_t)NROW * DLAT * 2); bf* ltl = (bf*)alloc((size_t)NROW * DLAT * 2);
    float* ltf = (float*)alloc((size_t)NROW * DLAT * 4);
    bf* d4h = (bf*)alloc((size_t)NROW * DH2 * 2);  bf* d4l = (bf*)alloc((size_t)NROW * DH2 * 2);
    bf* d5h = (bf*)alloc((size_t)NROW * DH1 * 2);  bf* d5l = (bf*)alloc((size_t)NROW * DH1 * 2);
    float* r1v = (float*)alloc((size_t)NROW * 4);
    float* r2v = (float*)alloc((size_t)NROW * 4);
    double* stats = (double*)alloc(5 * 8);

    // one fused split launch: x + 6 weights
    SplitArgs SA;
    const float* srcs[7] = { x, We1, We2, We3, Wd1, Wd2, Wd3 };
    bf* his[7] = { xh, w1h, w2h, w3h, w4h, w5h, w6h };
    bf* los[7] = { xl, w1l, w2l, w3l, w4l, w5l, w6l };
    unsigned ns[7] = { NROW * D0, DH1 * D0, DH2 * DH1, DLAT * DH2,
                       DH2 * DLAT, DH1 * DH2, D0 * DH1 };
    unsigned cum = 0;
    for (int i = 0; i < 7; ++i) {
        SA.s[i].src = srcs[i]; SA.s[i].hi = his[i]; SA.s[i].lo = los[i];
        SA.cum4[i] = cum; cum += ns[i] / 4;
    }
    SA.cum4[7] = cum;
    split_many<<<(cum + 255) / 256, 256, 0, stream>>>(SA, (int)cum);

    row_sumsq<<<NROW / 4, 256, 0, stream>>>(x, r1v, D0);
    init_stats<<<1, 64, 0, stream>>>(stats);

    // encoder
    gemm_lrelu<<<dim3(NROW / 128, DH1 / 128), 256, 0, stream>>>(
        xh, xl, w1h, w1l, be1, nullptr, h1h, h1l, DH1, D0);
    gemm_lrelu<<<dim3(NROW / 128, DH2 / 128), 256, 0, stream>>>(
        h1h, h1l, w2h, w2l, be2, nullptr, h2h, h2l, DH2, DH1);
    gemm_lrelu<<<dim3(NROW / 128, DLAT / 128), 256, 0, stream>>>(
        h2h, h2l, w3h, w3l, be3, ltf, lth, ltl, DLAT, DH2);
    row_sumsq<<<NROW / 4, 256, 0, stream>>>(ltf, r2v, DLAT);
    // decoder
    gemm_lrelu<<<dim3(NROW / 128, DH2 / 128), 256, 0, stream>>>(
        lth, ltl, w4h, w4l, bd1, nullptr, d4h, d4l, DH2, DLAT);
    gemm_lrelu<<<dim3(NROW / 128, DH1 / 128), 256, 0, stream>>>(
        d4h, d4l, w5h, w5l, bd2, nullptr, d5h, d5l, DH1, DH2);
    gemm_lrelu<<<dim3(NROW / 128, D0 / 128), 256, 0, stream>>>(
        d5h, d5l, w6h, w6l, bd3, out, nullptr, nullptr, D0, DH1);

    // fused pairwise-distance correlation statistics (triangle only: 528 blocks)
    pairwise_corr<<<dim3(528), 256, 0, stream>>>(xh, lth, r1v, r2v, stats);
    finalize_corr<<<1, 1, 0, stream>>>(stats, out + (size_t)NROW * D0);
}

// Round 3
// 323.762 us; speedup vs baseline: 1.1896x; 1.0353x over previous
//
#include <hip/hip_runtime.h>
#include <hip/hip_bf16.h>

#define NROW 4096
#define D0   1024
#define DH1  512
#define DH2  256
#define DLAT 128
#define SLOPE 0.01f

typedef float f32x4 __attribute__((ext_vector_type(4)));
typedef __bf16 bf16x8 __attribute__((ext_vector_type(8)));
typedef short short8 __attribute__((ext_vector_type(8)));

// counted vmcnt wait (literal N) — compiler memory fence via clobber
#define WAITV(N) asm volatile("s_waitcnt vmcnt(" #N ")" ::: "memory")
#define BARRIER() do { __builtin_amdgcn_s_barrier(); __builtin_amdgcn_sched_barrier(0); } while (0)

// ---- async global->LDS 16B (wave-uniform base + lane*16 dest) ----
__device__ __forceinline__ void gload_lds16(const void* gp, void* lp) {
    __builtin_amdgcn_global_load_lds(
        (const __attribute__((address_space(1))) void*)(unsigned long long)gp,
        (__attribute__((address_space(3))) void*)(unsigned int)(unsigned long long)lp,
        16, 0, 0);
}

// Stage a 128x32 bf16 tile into LDS [128][32] shorts with k-slot swizzle:
// stored slot t holds source slot s = t ^ ((row>>1)&3). LDS dest stays linear
// (lane*16B) as global_load_lds requires; swizzle applied to the SOURCE addr.
// 2 gload instructions per wave.
__device__ __forceinline__ void stage_tile(const __hip_bfloat16* __restrict__ src,
                                           int row0, int ldK, int k0,
                                           short* lds, int wave, int lane) {
#pragma unroll
    for (int i = 0; i < 2; ++i) {
        int lr = wave * 32 + i * 16 + (lane >> 2);   // tile row 0..127
        int t  = lane & 3;                            // stored slot
        int s  = t ^ ((lr >> 1) & 3);                 // source k-slot
        const __hip_bfloat16* gp = src + (size_t)(row0 + lr) * ldK + k0 + s * 8;
        short* lp = lds + lr * 32 + t * 8;            // wave base + lane*16B
        gload_lds16((const void*)gp, (void*)lp);
    }
}

// Read one 16x32 MFMA operand fragment (undo swizzle on the read side).
__device__ __forceinline__ bf16x8 read_frag(const short* lds, int row, int kslot) {
    int pos = kslot ^ ((row >> 1) & 3);
    short8 v = *reinterpret_cast<const short8*>(lds + row * 32 + pos * 8);
    union { short8 s; bf16x8 b; } u; u.s = v; return u.b;
}

// ---- split-precision GEMM: C = lrelu(A @ W^T + b), counted-vmcnt D=2 ----
// 3-MFMA split: ah*bh + ah*bl + al*bh (residual ~2^-18 relative).
__global__ __launch_bounds__(256) void gemm_lrelu(
    const __hip_bfloat16* __restrict__ Ah, const __hip_bfloat16* __restrict__ Al,
    const __hip_bfloat16* __restrict__ Wh, const __hip_bfloat16* __restrict__ Wl,
    const float* __restrict__ bias,
    float* __restrict__ Cf, __hip_bfloat16* __restrict__ Ch, __hip_bfloat16* __restrict__ Cl,
    int N, int K)
{
    __shared__ short sAh[2][128 * 32];
    __shared__ short sAl[2][128 * 32];
    __shared__ short sBh[2][128 * 32];
    __shared__ short sBl[2][128 * 32];
    const int tid = threadIdx.x, lane = tid & 63, wave = tid >> 6;
    const int wm = wave >> 1, wn = wave & 1;
    const int bm = blockIdx.x, bn = blockIdx.y;
    const int nk = K >> 5;

    f32x4 acc[4][4] = {};

    auto stage_all = [&](int buf, int ks) {   // 8 gloads per wave
        stage_tile(Ah, bm * 128, K, ks * 32, sAh[buf], wave, lane);
        stage_tile(Al, bm * 128, K, ks * 32, sAl[buf], wave, lane);
        stage_tile(Wh, bn * 128, K, ks * 32, sBh[buf], wave, lane);
        stage_tile(Wl, bn * 128, K, ks * 32, sBl[buf], wave, lane);
    };

    stage_all(0, 0);
#pragma unroll 1
    for (int ks = 0; ks < nk; ++ks) {
        WAITV(0);        // my step-ks loads done (issued one full compute-phase ago)
        BARRIER();       // all waves' step-ks loads done; prior-step reads retired
        if (ks + 1 < nk) stage_all((ks + 1) & 1, ks + 1);  // in flight across compute
        const int cur = ks & 1;
        bf16x8 ah[4], al[4], bh[4], bl[4];
#pragma unroll
        for (int m = 0; m < 4; ++m) {
            int r = wm * 64 + m * 16 + (lane & 15);
            ah[m] = read_frag(sAh[cur], r, lane >> 4);
            al[m] = read_frag(sAl[cur], r, lane >> 4);
        }
#pragma unroll
        for (int n = 0; n < 4; ++n) {
            int r = wn * 64 + n * 16 + (lane & 15);
            bh[n] = read_frag(sBh[cur], r, lane >> 4);
            bl[n] = read_frag(sBl[cur], r, lane >> 4);
        }
#pragma unroll
        for (int m = 0; m < 4; ++m)
#pragma unroll
            for (int n = 0; n < 4; ++n) {
                acc[m][n] = __builtin_amdgcn_mfma_f32_16x16x32_bf16(ah[m], bh[n], acc[m][n], 0, 0, 0);
                acc[m][n] = __builtin_amdgcn_mfma_f32_16x16x32_bf16(ah[m], bl[n], acc[m][n], 0, 0, 0);
                acc[m][n] = __builtin_amdgcn_mfma_f32_16x16x32_bf16(al[m], bh[n], acc[m][n], 0, 0, 0);
            }
    }

    float bcol[4];
#pragma unroll
    for (int n = 0; n < 4; ++n) bcol[n] = bias[bn * 128 + wn * 64 + n * 16 + (lane & 15)];

#pragma unroll
    for (int m = 0; m < 4; ++m)
#pragma unroll
        for (int n = 0; n < 4; ++n)
#pragma unroll
            for (int j = 0; j < 4; ++j) {
                int grow = bm * 128 + wm * 64 + m * 16 + (lane >> 4) * 4 + j;
                int gcol = bn * 128 + wn * 64 + n * 16 + (lane & 15);
                float v = acc[m][n][j] + bcol[n];
                v = v >= 0.f ? v : SLOPE * v;
                size_t idx = (size_t)grow * N + gcol;
                if (Cf) Cf[idx] = v;
                if (Ch) {
                    __hip_bfloat16 h = __float2bfloat16(v);
                    Ch[idx] = h;
                    Cl[idx] = __float2bfloat16(v - __bfloat162float(h));
                }
            }
}

// ---- fused pairwise-distance statistics, counted-vmcnt D=4 pipeline ----
// Triangle-only launch (528 blocks, XCD-chunked swizzle). Merged 36-step loop:
// steps 0..31 build G1 = x x^T (K=1024), steps 32..35 G2 = latent latent^T.
// 4 loads/wave/step -> steady-state wait vmcnt(8) (t+1, t+2 stay in flight).
__global__ __launch_bounds__(256) void pairwise_corr(
    const __hip_bfloat16* __restrict__ Xh, const __hip_bfloat16* __restrict__ Lh,
    const float* __restrict__ r1, const float* __restrict__ r2,
    double* __restrict__ stats)
{
    // XCD-chunked bijective swizzle: 528 = 8 * 66
    int bid = (blockIdx.x & 7) * 66 + (blockIdx.x >> 3);
    int rem = bid, bm = 0;
    while (rem >= 32 - bm) { rem -= 32 - bm; ++bm; }
    const int bn = bm + rem;                       // bm <= bn

    __shared__ short sA[4][128 * 32];
    __shared__ short sB[4][128 * 32];
    const int tid = threadIdx.x, lane = tid & 63, wave = tid >> 6;
    const int wm = wave >> 1, wn = wave & 1;

    f32x4 acc[4][4] = {};
    f32x4 acc2[4][4] = {};

    auto stage_step = [&](int buf, int t) {   // 4 gloads per wave
        if (t < 32) {
            stage_tile(Xh, bm * 128, D0, t * 32, sA[buf], wave, lane);
            stage_tile(Xh, bn * 128, D0, t * 32, sB[buf], wave, lane);
        } else {
            int k0 = (t - 32) * 32;
            stage_tile(Lh, bm * 128, DLAT, k0, sA[buf], wave, lane);
            stage_tile(Lh, bn * 128, DLAT, k0, sB[buf], wave, lane);
        }
    };

    stage_step(0, 0);
    stage_step(1, 1);
    stage_step(2, 2);
#pragma unroll 1
    for (int t = 0; t < 36; ++t) {
        if (t + 2 < 36)      WAITV(8);   // step-t loads done; t+1,t+2 in flight
        else if (t + 1 < 36) WAITV(4);
        else                 WAITV(0);
        BARRIER();
        if (t + 3 < 36) stage_step((t + 3) & 3, t + 3);  // targets buf[(t-1)&3]: safe post-barrier
        const int cur = t & 3;
        bf16x8 a[4], b[4];
#pragma unroll
        for (int m = 0; m < 4; ++m) a[m] = read_frag(sA[cur], wm * 64 + m * 16 + (lane & 15), lane >> 4);
#pragma unroll
        for (int n = 0; n < 4; ++n) b[n] = read_frag(sB[cur], wn * 64 + n * 16 + (lane & 15), lane >> 4);
        if (t < 32) {
#pragma unroll
            for (int m = 0; m < 4; ++m)
#pragma unroll
                for (int n = 0; n < 4; ++n)
                    acc[m][n] = __builtin_amdgcn_mfma_f32_16x16x32_bf16(a[m], b[n], acc[m][n], 0, 0, 0);
        } else {
#pragma unroll
            for (int m = 0; m < 4; ++m)
#pragma unroll
                for (int n = 0; n < 4; ++n)
                    acc2[m][n] = __builtin_amdgcn_mfma_f32_16x16x32_bf16(a[m], b[n], acc2[m][n], 0, 0, 0);
        }
    }

    float s1 = 0.f, s2 = 0.f, s11 = 0.f, s22 = 0.f, s12 = 0.f;
#pragma unroll
    for (int m = 0; m < 4; ++m)
#pragma unroll
        for (int n = 0; n < 4; ++n)
#pragma unroll
            for (int j = 0; j < 4; ++j) {
                int gi = bm * 128 + wm * 64 + m * 16 + (lane >> 4) * 4 + j;
                int gj = bn * 128 + wn * 64 + n * 16 + (lane & 15);
                float sq1 = r1[gi] + r1[gj] - 2.0f * acc[m][n][j];
                float d1v = (gi == gj || sq1 <= 0.f) ? 0.f : sqrtf(sq1);
                float sq2 = r2[gi] + r2[gj] - 2.0f * acc2[m][n][j];
                float d2v = (gi == gj || sq2 <= 0.f) ? 0.f : sqrtf(sq2);
                s1 += d1v; s2 += d2v;
                s11 += d1v * d1v; s22 += d2v * d2v; s12 += d1v * d2v;
            }

    float vals[5] = { s1, s2, s11, s22, s12 };
#pragma unroll
    for (int q = 0; q < 5; ++q)
        for (int off = 32; off; off >>= 1) vals[q] += __shfl_down(vals[q], off);

    __syncthreads();                 // done with LDS; reuse as reduce buffer
    float* red = (float*)sA;
    if (lane == 0) {
#pragma unroll
        for (int q = 0; q < 5; ++q) red[wave * 5 + q] = vals[q];
    }
    __syncthreads();
    if (tid == 0) {
        double w = (bm == bn) ? 1.0 : 2.0;
#pragma unroll
        for (int q = 0; q < 5; ++q) {
            double tt = (double)red[q] + (double)red[5 + q] + (double)red[10 + q] + (double)red[15 + q];
            atomicAdd(&stats[q], w * tt);
        }
    }
}

// ---- fused hi/lo split for x + all 6 weights (one launch) ----
struct SplitSeg { const float* src; __hip_bfloat16* hi; __hip_bfloat16* lo; };
struct SplitArgs { SplitSeg s[7]; unsigned cum4[8]; };  // boundaries in float4 units

__global__ void split_many(SplitArgs A, int total4) {
    int v = blockIdx.x * blockDim.x + threadIdx.x;
    if (v >= total4) return;
    int si = 0;
#pragma unroll
    for (int i = 1; i < 7; ++i) si = (v >= (int)A.cum4[i]) ? i : si;
    int local = v - (int)A.cum4[si];
    const float* src = A.s[si].src;
    __hip_bfloat16* hi = A.s[si].hi;
    __hip_bfloat16* lo = A.s[si].lo;
    float4 f = *(const float4*)(src + (size_t)local * 4);
    float fv[4] = { f.x, f.y, f.z, f.w };
#pragma unroll
    for (int j = 0; j < 4; ++j) {
        __hip_bfloat16 h = __float2bfloat16(fv[j]);
        hi[local * 4 + j] = h;
        lo[local * 4 + j] = __float2bfloat16(fv[j] - __bfloat162float(h));
    }
}

__global__ void row_sumsq(const float* __restrict__ X, float* __restrict__ r, int K) {
    int lane = threadIdx.x & 63;
    int row = blockIdx.x * (blockDim.x >> 6) + (threadIdx.x >> 6);
    const float* p = X + (size_t)row * K;
    float s = 0.f;
    for (int k = lane; k < K; k += 64) { float v = p[k]; s += v * v; }
    for (int off = 32; off; off >>= 1) s += __shfl_down(s, off);
    if (lane == 0) r[row] = s;
}

__global__ void init_stats(double* stats) {
    if (threadIdx.x < 5) stats[threadIdx.x] = 0.0;
}

__global__ void finalize_corr(const double* __restrict__ stats, float* __restrict__ corr_out) {
    double n = (double)NROW * (double)NROW;
    double s1 = stats[0], s2 = stats[1], s11 = stats[2], s22 = stats[3], s12 = stats[4];
    double m1 = s1 / n, m2 = s2 / n;
    double cov = s12 / n - m1 * m2;                  // biased (mean)
    double v1 = (s11 - n * m1 * m1) / (n - 1.0);     // unbiased (ddof=1)
    double v2 = (s22 - n * m2 * m2) / (n - 1.0);
    corr_out[0] = (float)(cov / sqrt(v1 * v2));
}

extern "C" void kernel_launch(void* const* d_in, const int* in_sizes, int n_in,
                              void* d_out, int out_size, void* d_ws, size_t ws_size,
                              hipStream_t stream) {
    const float* x   = (const float*)d_in[0];
    const float* We1 = (const float*)d_in[1];  const float* be1 = (const float*)d_in[2];
    const float* We2 = (const float*)d_in[3];  const float* be2 = (const float*)d_in[4];
    const float* We3 = (const float*)d_in[5];  const float* be3 = (const float*)d_in[6];
    const float* Wd1 = (const float*)d_in[7];  const float* bd1 = (const float*)d_in[8];
    const float* Wd2 = (const float*)d_in[9];  const float* bd2 = (const float*)d_in[10];
    const float* Wd3 = (const float*)d_in[11]; const float* bd3 = (const float*)d_in[12];
    float* out = (float*)d_out;

    char* ws = (char*)d_ws;
    size_t off = 0;
    auto alloc = [&](size_t bytes) -> char* {
        char* p = ws + off; off += (bytes + 255) & ~(size_t)255; return p;
    };
    typedef __hip_bfloat16 bf;
    bf* xh  = (bf*)alloc((size_t)NROW * D0 * 2);   bf* xl  = (bf*)alloc((size_t)NROW * D0 * 2);
    bf* w1h = (bf*)alloc((size_t)DH1 * D0 * 2);    bf* w1l = (bf*)alloc((size_t)DH1 * D0 * 2);
    bf* w2h = (bf*)alloc((size_t)DH2 * DH1 * 2);   bf* w2l = (bf*)alloc((size_t)DH2 * DH1 * 2);
    bf* w3h = (bf*)alloc((size_t)DLAT * DH2 * 2);  bf* w3l = (bf*)alloc((size_t)DLAT * DH2 * 2);
    bf* w4h = (bf*)alloc((size_t)DH2 * DLAT * 2);  bf* w4l = (bf*)alloc((size_t)DH2 * DLAT * 2);
    bf* w5h = (bf*)alloc((size_t)DH1 * DH2 * 2);   bf* w5l = (bf*)alloc((size_t)DH1 * DH2 * 2);
    bf* w6h = (bf*)alloc((size_t)D0 * DH1 * 2);    bf* w6l = (bf*)alloc((size_t)D0 * DH1 * 2);
    bf* h1h = (bf*)alloc((size_t)NROW * DH1 * 2);  bf* h1l = (bf*)alloc((size_t)NROW * DH1 * 2);
    bf* h2h = (bf*)alloc((size_t)NROW * DH2 * 2);  bf* h2l = (bf*)alloc((size_t)NROW * DH2 * 2);
    bf* lth = (bf*)alloc((size_t)NROW * DLAT * 2); bf* ltl = (bf*)alloc((size_t)NROW * DLAT * 2);
    float* ltf = (float*)alloc((size_t)NROW * DLAT * 4);
    bf* d4h = (bf*)alloc((size_t)NROW * DH2 * 2);  bf* d4l = (bf*)alloc((size_t)NROW * DH2 * 2);
    bf* d5h = (bf*)alloc((size_t)NROW * DH1 * 2);  bf* d5l = (bf*)alloc((size_t)NROW * DH1 * 2);
    float* r1v = (float*)alloc((size_t)NROW * 4);
    float* r2v = (float*)alloc((size_t)NROW * 4);
    double* stats = (double*)alloc(5 * 8);

    // one fused split launch: x + 6 weights
    SplitArgs SA;
    const float* srcs[7] = { x, We1, We2, We3, Wd1, Wd2, Wd3 };
    bf* his[7] = { xh, w1h, w2h, w3h, w4h, w5h, w6h };
    bf* los[7] = { xl, w1l, w2l, w3l, w4l, w5l, w6l };
    unsigned ns[7] = { NROW * D0, DH1 * D0, DH2 * DH1, DLAT * DH2,
                       DH2 * DLAT, DH1 * DH2, D0 * DH1 };
    unsigned cum = 0;
    for (int i = 0; i < 7; ++i) {
        SA.s[i].src = srcs[i]; SA.s[i].hi = his[i]; SA.s[i].lo = los[i];
        SA.cum4[i] = cum; cum += ns[i] / 4;
    }
    SA.cum4[7] = cum;
    split_many<<<(cum + 255) / 256, 256, 0, stream>>>(SA, (int)cum);

    row_sumsq<<<NROW / 4, 256, 0, stream>>>(x, r1v, D0);
    init_stats<<<1, 64, 0, stream>>>(stats);

    // encoder
    gemm_lrelu<<<dim3(NROW / 128, DH1 / 128), 256, 0, stream>>>(
        xh, xl, w1h, w1l, be1, nullptr, h1h, h1l, DH1, D0);
    gemm_lrelu<<<dim3(NROW / 128, DH2 / 128), 256, 0, stream>>>(
        h1h, h1l, w2h, w2l, be2, nullptr, h2h, h2l, DH2, DH1);
    gemm_lrelu<<<dim3(NROW / 128, DLAT / 128), 256, 0, stream>>>(
        h2h, h2l, w3h, w3l, be3, ltf, lth, ltl, DLAT, DH2);
    row_sumsq<<<NROW / 4, 256, 0, stream>>>(ltf, r2v, DLAT);
    // decoder
    gemm_lrelu<<<dim3(NROW / 128, DH2 / 128), 256, 0, stream>>>(
        lth, ltl, w4h, w4l, bd1, nullptr, d4h, d4l, DH2, DLAT);
    gemm_lrelu<<<dim3(NROW / 128, DH1 / 128), 256, 0, stream>>>(
        d4h, d4l, w5h, w5l, bd2, nullptr, d5h, d5l, DH1, DH2);
    gemm_lrelu<<<dim3(NROW / 128, D0 / 128), 256, 0, stream>>>(
        d5h, d5l, w6h, w6l, bd3, out, nullptr, nullptr, D0, DH1);

    // fused pairwise-distance correlation statistics (triangle only: 528 blocks)
    pairwise_corr<<<dim3(528), 256, 0, stream>>>(xh, lth, r1v, r2v, stats);
    finalize_corr<<<1, 1, 0, stream>>>(stats, out + (size_t)NROW * D0);
}